// Round 1
// baseline (1658.104 us; speedup 1.0000x reference)
//
#include <hip/hip_runtime.h>
#include <hip/hip_bf16.h>
#include <stdint.h>

// ---------------------------------------------------------------------------
// Fused concat-linear: y = x @ W^T + b, x:[8192,4096] f32, W:[12288,4096] f32,
// b:[12288]. Output = 3 chunks of [8192,4096] f32 concatenated flat.
// Strategy: cast x,W -> bf16 in d_ws, then m97-style 128x128-tile bf16 MFMA
// GEMM (16x16x32, BK=64, global_load_lds width=16, XOR-swizzled LDS chunks),
// fused bias + chunk-split epilogue.
// ---------------------------------------------------------------------------

typedef __attribute__((ext_vector_type(8))) short short8;   // 8 x bf16 (4 VGPR)
typedef __attribute__((ext_vector_type(4))) float f32x4;    // MFMA C/D

#define TILE 128
#define BK   64   // K-tile: 64 bf16 = 128 B = 8 chunks of 16 B per row

// round-to-nearest-even f32 -> bf16 (bit trick; inputs are finite normals)
__device__ __forceinline__ unsigned short f2bf(float f) {
  union { float f; unsigned u; } v; v.f = f;
  unsigned u = v.u;
  u += 0x7FFFu + ((u >> 16) & 1u);
  return (unsigned short)(u >> 16);
}

__global__ void cast_f32_to_bf16(const float* __restrict__ in,
                                 unsigned short* __restrict__ out, int n8) {
  int i = blockIdx.x * blockDim.x + threadIdx.x;
  if (i >= n8) return;
  const float4* p = (const float4*)in;
  float4 a = p[2 * i + 0];
  float4 b = p[2 * i + 1];
  uint4 o;
  o.x = (unsigned)f2bf(a.x) | ((unsigned)f2bf(a.y) << 16);
  o.y = (unsigned)f2bf(a.z) | ((unsigned)f2bf(a.w) << 16);
  o.z = (unsigned)f2bf(b.x) | ((unsigned)f2bf(b.y) << 16);
  o.w = (unsigned)f2bf(b.z) | ((unsigned)f2bf(b.w) << 16);
  ((uint4*)out)[i] = o;
}

// LDS layout: tile stored as [row][8 chunks of 16B], with chunk column
// XOR-swizzled by (row & 7). global_load_lds requires contiguous LDS dest
// (wave base + lane*16), so the swizzle is applied on the GLOBAL source
// address at staging time and undone at ds_read time. This breaks the
// 16-way bank conflict of the naive [row][64] layout (row stride = 128 B =
// exactly 32 banks) down to the structural 8-phase minimum for b128 reads.

template<bool USE_WS>
__global__ __launch_bounds__(256)
void gemm_bias_split(const unsigned short* __restrict__ Abf,  // [M][K] bf16 (ws)
                     const unsigned short* __restrict__ Bbf,  // [N][K] bf16 (ws)
                     const float* __restrict__ Af32,          // x  [M][K] f32
                     const float* __restrict__ Bf32,          // W  [N][K] f32
                     const float* __restrict__ bias,          // [N]
                     float* __restrict__ out,                 // 3 x [M][H]
                     int M, int N, int K, int H) {
  __shared__ short sA[TILE * BK];   // 16 KiB
  __shared__ short sB[TILE * BK];   // 16 KiB

  const int tid  = threadIdx.x;
  const int lane = tid & 63;
  const int r16  = lane & 15;       // row within a 16x16 MFMA tile
  const int q    = lane >> 4;       // k-quad (0..3)
  const int wave = tid >> 6;        // 4 waves, 2x2 over the 128x128 tile
  const int wm   = (wave & 1) * 64;
  const int wn   = (wave >> 1) * 64;
  const int m0   = blockIdx.y * TILE;
  const int n0   = blockIdx.x * TILE;

  f32x4 acc[4][4];
#pragma unroll
  for (int i = 0; i < 4; ++i)
#pragma unroll
    for (int j = 0; j < 4; ++j)
      acc[i][j] = (f32x4){0.f, 0.f, 0.f, 0.f};

  for (int k0 = 0; k0 < K; k0 += BK) {
    __syncthreads();  // previous compute done before LDS overwrite
#pragma unroll
    for (int it = 0; it < 4; ++it) {
      const int chunk = it * 256 + tid;      // 0..1023: LDS slot (row, c)
      const int row   = chunk >> 3;
      const int c     = chunk & 7;
      const int cs    = c ^ (row & 7);       // swizzled global chunk column
      if (USE_WS) {
        const unsigned short* gA = Abf + (size_t)(m0 + row) * K + (k0 + cs * 8);
        const unsigned short* gB = Bbf + (size_t)(n0 + row) * K + (k0 + cs * 8);
        __builtin_amdgcn_global_load_lds(
            (const __attribute__((address_space(1))) unsigned int*)gA,
            (__attribute__((address_space(3))) unsigned int*)&sA[chunk * 8],
            16, 0, 0);
        __builtin_amdgcn_global_load_lds(
            (const __attribute__((address_space(1))) unsigned int*)gB,
            (__attribute__((address_space(3))) unsigned int*)&sB[chunk * 8],
            16, 0, 0);
      } else {
        const float* gA = Af32 + (size_t)(m0 + row) * K + (k0 + cs * 8);
        const float* gB = Bf32 + (size_t)(n0 + row) * K + (k0 + cs * 8);
        float4 a0 = ((const float4*)gA)[0], a1 = ((const float4*)gA)[1];
        float4 b0 = ((const float4*)gB)[0], b1 = ((const float4*)gB)[1];
        short8 va, vb;
        va[0] = (short)f2bf(a0.x); va[1] = (short)f2bf(a0.y);
        va[2] = (short)f2bf(a0.z); va[3] = (short)f2bf(a0.w);
        va[4] = (short)f2bf(a1.x); va[5] = (short)f2bf(a1.y);
        va[6] = (short)f2bf(a1.z); va[7] = (short)f2bf(a1.w);
        vb[0] = (short)f2bf(b0.x); vb[1] = (short)f2bf(b0.y);
        vb[2] = (short)f2bf(b0.z); vb[3] = (short)f2bf(b0.w);
        vb[4] = (short)f2bf(b1.x); vb[5] = (short)f2bf(b1.y);
        vb[6] = (short)f2bf(b1.z); vb[7] = (short)f2bf(b1.w);
        *(short8*)&sA[chunk * 8] = va;
        *(short8*)&sB[chunk * 8] = vb;
      }
    }
    __syncthreads();  // drains vmcnt(0): global_load_lds data visible

#pragma unroll
    for (int ks = 0; ks < 2; ++ks) {
      short8 af[4], bf[4];
#pragma unroll
      for (int i = 0; i < 4; ++i) {
        const int row = wm + i * 16 + r16;       // A[m = lane&15][k = q*8+j]
        const int cc  = ks * 4 + q;
        af[i] = *(const short8*)&sA[row * BK + (cc ^ (row & 7)) * 8];
      }
#pragma unroll
      for (int j = 0; j < 4; ++j) {
        const int row = wn + j * 16 + r16;       // B[k = q*8+j][n = lane&15]
        const int cc  = ks * 4 + q;
        bf[j] = *(const short8*)&sB[row * BK + (cc ^ (row & 7)) * 8];
      }
#pragma unroll
      for (int i = 0; i < 4; ++i)
#pragma unroll
        for (int j = 0; j < 4; ++j)
          acc[i][j] = __builtin_amdgcn_mfma_f32_16x16x32_bf16(
              af[i], bf[j], acc[i][j], 0, 0, 0);
    }
  }

  // Epilogue: +bias, write into concat-split layout.
  // C/D layout: col(n) = lane&15, row(m) = (lane>>4)*4 + reg   [m89/m91]
  float bj[4];
#pragma unroll
  for (int j = 0; j < 4; ++j) bj[j] = bias[n0 + wn + j * 16 + r16];
  const size_t chunk_elems = (size_t)M * H;
#pragma unroll
  for (int j = 0; j < 4; ++j) {
    const int n  = n0 + wn + j * 16 + r16;
    const int ci = n / H;                    // which of the 3 output chunks
    const int h  = n - ci * H;
    float* obase = out + (size_t)ci * chunk_elems + h;
#pragma unroll
    for (int i = 0; i < 4; ++i) {
      const int mb = m0 + wm + i * 16 + q * 4;
#pragma unroll
      for (int rr = 0; rr < 4; ++rr) {
        obase[(size_t)(mb + rr) * H] = acc[i][j][rr] + bj[j];
      }
    }
  }
}

extern "C" void kernel_launch(void* const* d_in, const int* in_sizes, int n_in,
                              void* d_out, int out_size, void* d_ws, size_t ws_size,
                              hipStream_t stream) {
  const float* x = (const float*)d_in[0];
  const float* W = (const float*)d_in[1];
  const float* b = (const float*)d_in[2];
  float* out = (float*)d_out;

  const int N = in_sizes[2];                 // 12288
  const int K = in_sizes[1] / N;             // 4096
  const int M = in_sizes[0] / K;             // 8192 (= 4*2048)
  const int H = N / 3;                       // 4096

  dim3 grid(N / TILE, M / TILE);             // 96 x 64 = 6144 blocks
  const size_t nA = (size_t)M * K;
  const size_t nB = (size_t)N * K;

  if (ws_size >= (nA + nB) * sizeof(unsigned short)) {
    unsigned short* xa = (unsigned short*)d_ws;
    unsigned short* wb = xa + nA;
    cast_f32_to_bf16<<<(int)((nA / 8 + 255) / 256), 256, 0, stream>>>(x, xa, (int)(nA / 8));
    cast_f32_to_bf16<<<(int)((nB / 8 + 255) / 256), 256, 0, stream>>>(W, wb, (int)(nB / 8));
    gemm_bias_split<true><<<grid, 256, 0, stream>>>(xa, wb, x, W, b, out, M, N, K, H);
  } else {
    // workspace too small: stage via VGPR round-trip with inline f32->bf16
    gemm_bias_split<false><<<grid, 256, 0, stream>>>(nullptr, nullptr, x, W, b, out, M, N, K, H);
  }
}